// Round 4
// baseline (111.714 us; speedup 1.0000x reference)
//
#include <hip/hip_runtime.h>
#include <hip/hip_bf16.h>

// JPEG 8x8 block DCT + quantization.
// image: [16,1,1024,1024] fp32; quality_factor: [16] fp32
// out:   [16,64,128,128] fp32, channel = k*8+l, out = (C @ (blk-128) @ C^T) / (factor*Q)
//
// R4 changes vs R3 (kernel ~37us, ~2x over clean cycle budget; R2's VGPR_Count=48
// proved the compiler was spilling/rematerializing tmp[64]; R3's 128-VGPR cap is
// still below the ~150 this dataflow needs live):
//  - __launch_bounds__(256, 3): VGPR cap ~170 -> pix[16]+tmp[64] fully live, no spill,
//    all 16 loads in flight (12 waves/CU x 16KB >> 9KB/CU needed for HBM saturation)
//  - load all 16 float4 up-front, then compute
//  - fold the -128 subtract into a single DC correction: out[0][0] -= 1024 pre-scale
//    (DCT rows k>0 sum to zero, so constants annihilate) -- removes 64 VALU/thread

#define BS 8
#define HPIX 1024
#define WPIX 1024
#define HB (HPIX / BS)   // 128
#define WB (WPIX / BS)   // 128
#define BATCH 16

// Orthonormal DCT-II matrix C[k][n] = f_k * cos(pi*(2n+1)*k/16), fp32-rounded.
constexpr float DCT[8][8] = {
  { 0.35355339059327373f,  0.35355339059327373f,  0.35355339059327373f,  0.35355339059327373f,
    0.35355339059327373f,  0.35355339059327373f,  0.35355339059327373f,  0.35355339059327373f },
  { 0.49039264020161522f,  0.41573480615127262f,  0.27778511650980114f,  0.09754516100806413f,
   -0.09754516100806413f, -0.27778511650980114f, -0.41573480615127262f, -0.49039264020161522f },
  { 0.46193976625564337f,  0.19134171618254492f, -0.19134171618254492f, -0.46193976625564337f,
   -0.46193976625564337f, -0.19134171618254492f,  0.19134171618254492f,  0.46193976625564337f },
  { 0.41573480615127262f, -0.09754516100806413f, -0.49039264020161522f, -0.27778511650980114f,
    0.27778511650980114f,  0.49039264020161522f,  0.09754516100806413f, -0.41573480615127262f },
  { 0.35355339059327373f, -0.35355339059327373f, -0.35355339059327373f,  0.35355339059327373f,
    0.35355339059327373f, -0.35355339059327373f, -0.35355339059327373f,  0.35355339059327373f },
  { 0.27778511650980114f, -0.49039264020161522f,  0.09754516100806413f,  0.41573480615127262f,
   -0.41573480615127262f, -0.09754516100806413f,  0.49039264020161522f, -0.27778511650980114f },
  { 0.19134171618254492f, -0.46193976625564337f,  0.46193976625564337f, -0.19134171618254492f,
   -0.19134171618254492f,  0.46193976625564337f, -0.46193976625564337f,  0.19134171618254492f },
  { 0.09754516100806413f, -0.27778511650980114f,  0.41573480615127262f, -0.49039264020161522f,
    0.49039264020161522f, -0.41573480615127262f,  0.27778511650980114f, -0.09754516100806413f },
};

// 1 / (LUMINANCE_QUANTIZATION_TABLE / 100) = 100 / table entry
constexpr float INVQ[8][8] = {
  { 6.25f,              9.09090909090909f,  10.0f,              6.25f,
    4.16666666666667f,  2.5f,               1.96078431372549f,  1.63934426229508f },
  { 8.33333333333333f,  8.33333333333333f,  7.14285714285714f,  5.26315789473684f,
    3.84615384615385f,  1.72413793103448f,  1.66666666666667f,  1.81818181818182f },
  { 7.14285714285714f,  7.69230769230769f,  6.25f,              4.16666666666667f,
    2.5f,               1.75438596491228f,  1.44927536231884f,  1.78571428571429f },
  { 7.14285714285714f,  5.88235294117647f,  4.54545454545455f,  3.44827586206897f,
    1.96078431372549f,  1.14942528735632f,  1.25f,              1.61290322580645f },
  { 5.55555555555556f,  4.54545454545455f,  2.70270270270270f,  1.78571428571429f,
    1.47058823529412f,  0.91743119266055f,  0.970873786407767f, 1.29870129870130f },
  { 4.16666666666667f,  2.77777777777778f,  1.81818181818182f,  1.5625f,
    1.23456790123457f,  0.961538461538462f, 0.884955752212389f, 1.08695652173913f },
  { 2.04081632653061f,  1.5625f,            1.28205128205128f,  1.14942528735632f,
    0.970873786407767f, 0.826446280991736f, 0.833333333333333f, 0.990099009900990f },
  { 1.38888888888889f,  1.08695652173913f,  1.05263157894737f,  1.02040816326531f,
    0.892857142857143f, 1.0f,               0.970873786407767f, 1.01010101010101f },
};

// WG = 256 threads = 2 consecutive block-rows (h0, h0+1) x 128 block-cols, one batch.
__global__ __launch_bounds__(256, 3) void jpeg_dct_q_kernel(
    const float* __restrict__ img,
    const float* __restrict__ qf,
    float* __restrict__ out)
{
    // ping-pong staging: [buf][hsub][l][w]; 2*2*8*128*4B = 16 KB
    __shared__ float lds[2][2][8][WB];

    const int t = threadIdx.x;
    const int g = blockIdx.x;
    const int b = g >> 6;                 // batch
    const int h0 = (g & 63) << 1;         // first block-row of the pair
    const int w = t & (WB - 1);           // block col
    const int hsub = t >> 7;              // 0/1 within the pair
    const int h = h0 + hsub;

    const float* rowbase = img + ((size_t)b << 20) + (size_t)(h * BS) * WPIX + (size_t)(w * BS);

    // Issue ALL 16 loads up-front (16 KB in flight per wave).
    float4 pix[16];
#pragma unroll
    for (int n = 0; n < 8; ++n) {
        const float4* p = reinterpret_cast<const float4*>(rowbase + n * WPIX);
        pix[2 * n]     = p[0];
        pix[2 * n + 1] = p[1];
    }

    // Stage 1: tmp[k][m] = sum_n DCT[k][n] * pix[n][m]   (no -128: folded into DC)
    float tmp[8][8];
#pragma unroll
    for (int k = 0; k < 8; ++k)
#pragma unroll
        for (int m = 0; m < 8; ++m)
            tmp[k][m] = 0.0f;

#pragma unroll
    for (int n = 0; n < 8; ++n) {
        float r[8];
        r[0] = pix[2 * n].x;     r[1] = pix[2 * n].y;
        r[2] = pix[2 * n].z;     r[3] = pix[2 * n].w;
        r[4] = pix[2 * n + 1].x; r[5] = pix[2 * n + 1].y;
        r[6] = pix[2 * n + 1].z; r[7] = pix[2 * n + 1].w;
#pragma unroll
        for (int k = 0; k < 8; ++k) {
            const float cf = DCT[k][n];   // constexpr -> immediate
#pragma unroll
            for (int m = 0; m < 8; ++m)
                tmp[k][m] = fmaf(cf, r[m], tmp[k][m]);
        }
    }

    // Quantization scale: factor = QF<50 ? 5000/QF : 200-2*QF
    const float q = qf[b];
    const float factor = (q < 50.0f) ? (5000.0f / q) : (200.0f - 2.0f * q);
    const float rf = 1.0f / factor;

    // Phase-2 (flush) thread mapping: thread t -> (p_hsub, p_l, 2 w-groups of 4)
    const int p_hsub = t >> 7;
    const int p_l = (t >> 4) & 7;
    const int p_g0 = t & 15;
    const size_t obatch = (size_t)b << 20;

    // Per DCT row k: compute 8 channels -> LDS (ping-pong) -> float4 stores.
    // One barrier per k is sufficient: reads of buf at k precede the barrier at
    // k+1, which precedes the next write of that buf at k+2.
#pragma unroll
    for (int k = 0; k < 8; ++k) {
        const int buf = k & 1;
#pragma unroll
        for (int l = 0; l < 8; ++l) {
            float s = 0.0f;
#pragma unroll
            for (int m = 0; m < 8; ++m)
                s = fmaf(DCT[l][m], tmp[k][m], s);
            if (k == 0 && l == 0)
                s -= 1024.0f;   // DC correction for the folded -128 pre-subtract
            lds[buf][hsub][l][w] = s * rf * INVQ[k][l];
        }
        __syncthreads();
#pragma unroll
        for (int it = 0; it < 2; ++it) {
            const int grp = p_g0 + 16 * it;          // w-group: 4 consecutive w
            float4 v = *reinterpret_cast<const float4*>(&lds[buf][p_hsub][p_l][4 * grp]);
            float* dst = out + obatch + (size_t)(k * 8 + p_l) * (HB * WB)
                             + (size_t)(h0 + p_hsub) * WB + 4 * grp;
            *reinterpret_cast<float4*>(dst) = v;
        }
    }
}

extern "C" void kernel_launch(void* const* d_in, const int* in_sizes, int n_in,
                              void* d_out, int out_size, void* d_ws, size_t ws_size,
                              hipStream_t stream) {
    const float* img = (const float*)d_in[0];
    const float* qf  = (const float*)d_in[1];
    float* out = (float*)d_out;

    const int grid = BATCH * (HB / 2);   // 1024 WGs: one per (batch, block-row pair)
    const int block = 256;

    jpeg_dct_q_kernel<<<grid, block, 0, stream>>>(img, qf, out);
}

// Round 5
// 111.484 us; speedup vs baseline: 1.0021x; 1.0021x over previous
//
#include <hip/hip_runtime.h>
#include <hip/hip_bf16.h>

// JPEG 8x8 block DCT + quantization.
// image: [16,1,1024,1024] fp32; quality_factor: [16] fp32
// out:   [16,64,128,128] fp32, channel = k*8+l, out = (C @ (blk-128) @ C^T) / (factor*Q)
//
// R5: full restructure for WAVE SUPPLY. R2-R4 (1 thread per 8x8 block) fix the
// grid at 4096 waves = 16 waves/CU total -- latency-bound at VALUBusy ~19%,
// kernel ~37us regardless of per-thread tuning. Now: 8 threads per block
// (thread = one pixel column) -> 32768 waves = 128 waves/CU supply, 8/SIMD
// resident. Per-wave issue ~400cyc, 2 barriers (vs 8), coalesced dword loads,
// float4 stores of full 128B lines. Expect HBM/LDS-bound ~18-23us kernel.
//
// WG = 256 threads = 32 blocks (8 threads each), covering 32 consecutive block
// cols at one (batch, block-row). Grid = 16 * 128 * 4 = 8192 WGs.

#define BS 8
#define HPIX 1024
#define WPIX 1024
#define HB (HPIX / BS)   // 128
#define WB (WPIX / BS)   // 128
#define BATCH 16

#define S_A 9    // ldsA inner stride (pad 8->9: breaks pow2 bank stride)
#define S_B 33   // ldsB row stride (32 w + 1 pad)

// Orthonormal DCT-II matrix C[k][n] = f_k * cos(pi*(2n+1)*k/16), fp32-rounded.
constexpr float DCT[8][8] = {
  { 0.35355339059327373f,  0.35355339059327373f,  0.35355339059327373f,  0.35355339059327373f,
    0.35355339059327373f,  0.35355339059327373f,  0.35355339059327373f,  0.35355339059327373f },
  { 0.49039264020161522f,  0.41573480615127262f,  0.27778511650980114f,  0.09754516100806413f,
   -0.09754516100806413f, -0.27778511650980114f, -0.41573480615127262f, -0.49039264020161522f },
  { 0.46193976625564337f,  0.19134171618254492f, -0.19134171618254492f, -0.46193976625564337f,
   -0.46193976625564337f, -0.19134171618254492f,  0.19134171618254492f,  0.46193976625564337f },
  { 0.41573480615127262f, -0.09754516100806413f, -0.49039264020161522f, -0.27778511650980114f,
    0.27778511650980114f,  0.49039264020161522f,  0.09754516100806413f, -0.41573480615127262f },
  { 0.35355339059327373f, -0.35355339059327373f, -0.35355339059327373f,  0.35355339059327373f,
    0.35355339059327373f, -0.35355339059327373f, -0.35355339059327373f,  0.35355339059327373f },
  { 0.27778511650980114f, -0.49039264020161522f,  0.09754516100806413f,  0.41573480615127262f,
   -0.41573480615127262f, -0.09754516100806413f,  0.49039264020161522f, -0.27778511650980114f },
  { 0.19134171618254492f, -0.46193976625564337f,  0.46193976625564337f, -0.19134171618254492f,
   -0.19134171618254492f,  0.46193976625564337f, -0.46193976625564337f,  0.19134171618254492f },
  { 0.09754516100806413f, -0.27778511650980114f,  0.41573480615127262f, -0.49039264020161522f,
    0.49039264020161522f, -0.41573480615127262f,  0.27778511650980114f, -0.09754516100806413f },
};

// 1 / (LUMINANCE_QUANTIZATION_TABLE / 100) = 100 / table entry
constexpr float INVQ[8][8] = {
  { 6.25f,              9.09090909090909f,  10.0f,              6.25f,
    4.16666666666667f,  2.5f,               1.96078431372549f,  1.63934426229508f },
  { 8.33333333333333f,  8.33333333333333f,  7.14285714285714f,  5.26315789473684f,
    3.84615384615385f,  1.72413793103448f,  1.66666666666667f,  1.81818181818182f },
  { 7.14285714285714f,  7.69230769230769f,  6.25f,              4.16666666666667f,
    2.5f,               1.75438596491228f,  1.44927536231884f,  1.78571428571429f },
  { 7.14285714285714f,  5.88235294117647f,  4.54545454545455f,  3.44827586206897f,
    1.96078431372549f,  1.14942528735632f,  1.25f,              1.61290322580645f },
  { 5.55555555555556f,  4.54545454545455f,  2.70270270270270f,  1.78571428571429f,
    1.47058823529412f,  0.91743119266055f,  0.970873786407767f, 1.29870129870130f },
  { 4.16666666666667f,  2.77777777777778f,  1.81818181818182f,  1.5625f,
    1.23456790123457f,  0.961538461538462f, 0.884955752212389f, 1.08695652173913f },
  { 2.04081632653061f,  1.5625f,            1.28205128205128f,  1.14942528735632f,
    0.970873786407767f, 0.826446280991736f, 0.833333333333333f, 0.990099009900990f },
  { 1.38888888888889f,  1.08695652173913f,  1.05263157894737f,  1.02040816326531f,
    0.892857142857143f, 1.0f,               0.970873786407767f, 1.01010101010101f },
};

__global__ __launch_bounds__(256, 8) void jpeg_dct_q_kernel(
    const float* __restrict__ img,
    const float* __restrict__ qf,
    float* __restrict__ out)
{
    __shared__ float ldsA[32 * 8 * S_A];   // [blk][m][k] padded: 9216 B
    __shared__ float ldsB[64 * S_B];       // [ch][w'] padded:   8448 B
    __shared__ float lds_invq[64];         // per-channel 1/Q:    256 B

    const int t  = threadIdx.x;
    const int wg = blockIdx.x;
    const int b  = wg >> 9;                // batch       (uniform)
    const int h  = (wg >> 2) & 127;        // block row   (uniform)
    const int w0 = (wg & 3) << 5;          // first of 32 block cols (uniform)
    const int m   = t & 7;                 // pixel column within block
    const int blk = t >> 3;                // block 0..31 within WG

    // Stage invq table once (lane 0 only; compile-time indices -> immediates;
    // visibility to all threads guaranteed by the barriers below).
    if (t == 0) {
#pragma unroll
        for (int ch = 0; ch < 64; ++ch)
            lds_invq[ch] = INVQ[ch >> 3][ch & 7];
    }

    // Coalesced column loads: wave = 256 consecutive floats per pixel row.
    const float* colbase = img + ((size_t)b << 20)
                               + (size_t)(h * BS) * WPIX
                               + (size_t)((w0 + blk) * BS + m);
    float pix[8];
#pragma unroll
    for (int n = 0; n < 8; ++n)
        pix[n] = colbase[(size_t)n * WPIX];

    // Stage A: column DCT. tk[k] = sum_n C[k][n]*(pix[n]-128); the -128 folds
    // into DC only (rows k>0 of C sum to 0): tk[0] -= 128*8*C[0][0].
#pragma unroll
    for (int k = 0; k < 8; ++k) {
        float s = 0.0f;
#pragma unroll
        for (int n = 0; n < 8; ++n)
            s = fmaf(DCT[k][n], pix[n], s);
        if (k == 0) s -= 362.03867196751236f;   // 1024 * 0.35355339059327373
        ldsA[(blk * 8 + m) * S_A + k] = s;
    }
    __syncthreads();

    // Stage B: row DCT. Thread (blk, j) owns output row k=j of its block:
    // reads tmp[j][m] for m=0..7 (the 8 sibling columns), computes all l.
    const int j = t & 7;
    float tt[8];
#pragma unroll
    for (int mm = 0; mm < 8; ++mm)
        tt[mm] = ldsA[(blk * 8 + mm) * S_A + j];
#pragma unroll
    for (int l = 0; l < 8; ++l) {
        float s = 0.0f;
#pragma unroll
        for (int mm = 0; mm < 8; ++mm)
            s = fmaf(DCT[l][mm], tt[mm], s);
        ldsB[(j * 8 + l) * S_B + blk] = s;      // [ch][w'] staging
    }
    __syncthreads();

    // Quantization scale: factor = QF<50 ? 5000/QF : 200-2*QF  (uniform per WG)
    const float q = qf[b];
    const float factor = (q < 50.0f) ? (5000.0f / q) : (200.0f - 2.0f * q);
    const float rf = 1.0f / factor;

    // Flush: 512 float4 groups (64 ch x 8 groups of 4 w). Each store instr
    // covers 8 channel planes x 128B full lines, 16B aligned.
#pragma unroll
    for (int it = 0; it < 2; ++it) {
        const int g   = t + 256 * it;   // 0..511
        const int ch  = g >> 3;         // 0..63
        const int grp = g & 7;          // group of 4 w
        const float qsc = rf * lds_invq[ch];
        const float* src = &ldsB[ch * S_B + 4 * grp];
        float4 v;
        v.x = src[0] * qsc;
        v.y = src[1] * qsc;
        v.z = src[2] * qsc;
        v.w = src[3] * qsc;
        float* dst = out + ((size_t)b << 20)
                         + (size_t)ch * (HB * WB)
                         + (size_t)h * WB
                         + (size_t)(w0 + 4 * grp);
        *reinterpret_cast<float4*>(dst) = v;
    }
}

extern "C" void kernel_launch(void* const* d_in, const int* in_sizes, int n_in,
                              void* d_out, int out_size, void* d_ws, size_t ws_size,
                              hipStream_t stream) {
    const float* img = (const float*)d_in[0];
    const float* qf  = (const float*)d_in[1];
    float* out = (float*)d_out;

    const int grid = BATCH * HB * 4;   // 8192 WGs: (batch, block-row, w-quarter)
    const int block = 256;

    jpeg_dct_q_kernel<<<grid, block, 0, stream>>>(img, qf, out);
}